// Round 3
// baseline (262.377 us; speedup 1.0000x reference)
//
#include <hip/hip_runtime.h>
#include <stdint.h>

#define C_INPUTS 41024
#define C_KEFF   40960   // last 64 cols of W are zero -> skipped exactly
#define C_L1     256
#define C_NT32   (C_KEFF / 32)                    // 1280 32-k tiles
#define WS_W_BYTES ((size_t)C_L1 * C_KEFF * 2)    // 20,971,520

typedef __attribute__((ext_vector_type(8))) short short8;
typedef __attribute__((ext_vector_type(4))) float f32x4;

__device__ __forceinline__ uint16_t bf16_rtne(float f) {
  uint32_t u = __builtin_bit_cast(uint32_t, f);
  u += 0x7fffu + ((u >> 16) & 1u);
  return (uint16_t)(u >> 16);
}

__device__ __forceinline__ short8 pack_bf16x8(float4 a, float4 b) {
  union { uint16_t h[8]; short8 v; } u;
  u.h[0] = bf16_rtne(a.x); u.h[1] = bf16_rtne(a.y);
  u.h[2] = bf16_rtne(a.z); u.h[3] = bf16_rtne(a.w);
  u.h[4] = bf16_rtne(b.x); u.h[5] = bf16_rtne(b.y);
  u.h[6] = bf16_rtne(b.z); u.h[7] = bf16_rtne(b.w);
  return u.v;
}

// ---------------------------------------------------------------------------
// Kernel 1: W [256, 41024] f32 -> bf16 workspace in FRAGMENT-MAJOR 32-k tiles.
// Tile kt: elem(kt, f, l, j) = W[16f + (l&15)][kt*32 + (l>>4)*8 + j]
// (f = 16-col group 0..15, l = frag lane, j = 0..7). The GEMM reads each
// fragment as one contiguous 1KB wave load (lane*16B) straight to VGPRs.
// ---------------------------------------------------------------------------
__global__ __launch_bounds__(256) void k_convert_w(const float* __restrict__ W,
                                                   uint16_t* __restrict__ wsW) {
  const int kt = blockIdx.x;    // 0..1279
  const int t  = threadIdx.x;
  const int l  = t & 63;
  const int fb = t >> 6;        // 0..3
  const int rm = l & 15;
  const int kg = l >> 4;        // 0..3
  const int kcol = kt * 32 + kg * 8;
  uint16_t* dst = wsW + (size_t)kt * (C_L1 * 32) + (size_t)l * 8;
#pragma unroll
  for (int q = 0; q < 4; ++q) {
    const int f = fb * 4 + q;
    const int row = f * 16 + rm;
    const float4* s = (const float4*)(W + (size_t)row * C_INPUTS + kcol);
    *(short8*)(dst + (size_t)f * 512) = pack_bf16x8(s[0], s[1]);
  }
}

// ---------------------------------------------------------------------------
// Kernel 2: GEMM. Block = (mb, ks): 64 rows x 256 cols over KCHUNK k.
// 4 waves; wave owns a 64x64 N-quadrant (4x4 frags of 16x16x32 bf16).
// W: global(L2) -> registers directly (fragment-major ws), half-iter
//    double-buffered wX/wY. NO global_load_lds -> no vmcnt(0) barrier drain.
// A: f32 global -> regs (distance 2) -> cvt bf16 -> 8KB LDS tile (write once,
//    read by 4 waves), 2 buffers, one __syncthreads per 64-k iter.
// Partials f32 -> wsP[ks][4096][256].
// ---------------------------------------------------------------------------
template<int KSPLIT>
__global__ __launch_bounds__(256, 3) void k_gemm(const float* __restrict__ w_in,
                                                 const float* __restrict__ b_in,
                                                 const uint16_t* __restrict__ wsW,
                                                 float* __restrict__ wsP) {
  constexpr int KCHUNK = C_KEFF / KSPLIT;
  constexpr int NITER  = KCHUNK / 64;     // 40 (KSPLIT=16) / 80 (KSPLIT=8), even
  __shared__ short8 abuf[2][512];          // 2 x 8KB A tile, fragment-major

  const int bid  = blockIdx.x;
  const int ks   = bid % KSPLIT;  // XCD-affine: W chunk(s) for this ks stay in one L2
  const int mb   = bid / KSPLIT;  // 0..63
  const int tid  = threadIdx.x;
  const int wave = tid >> 6;
  const int lane = tid & 63;
  const int lrow = lane & 15;
  const int lg   = lane >> 4;

  const float* Abase = (mb < 32) ? (w_in + (size_t)mb * 64 * C_INPUTS)
                                 : (b_in + (size_t)(mb - 32) * 64 * C_INPUTS);
  const int ar = tid >> 2;   // row 0..63 (4 threads per row)
  const int ac = tid & 3;    // 8-f32 chunk within each 32-k half
  const float* aptr = Abase + (size_t)ar * C_INPUTS + ks * KCHUNK + ac * 8;

  // A LDS slots: region (kk*4 + mi) of 64 slots; thread writes frag-lane
  // ac*16 + (ar&15) -> each wave's ds_write covers one full contiguous 1KB
  // region (conflict-free); reads are region + lane*16 (conflict-free).
  const int slot0 = (ar >> 4) * 64 + ac * 16 + (ar & 15);  // kk=0
  const int slot1 = slot0 + 256;                            // kk=1

  // W fragment source: tile elems = kt*8192 + f*512 + lane*8, f = wave*4+nj
  const uint16_t* wbase = wsW + (size_t)(ks * (KCHUNK / 32)) * 8192
                        + wave * 2048 + lane * 8;

  f32x4 acc[4][4];
#pragma unroll
  for (int i = 0; i < 4; ++i)
#pragma unroll
    for (int j = 0; j < 4; ++j) acc[i][j] = (f32x4){0.f, 0.f, 0.f, 0.f};

  float4 aA[4], aB[4];
  short8 wX[4], wY[4];

#define LOAD_A(DST, T) do {                                    \
    const float* p_ = aptr + (size_t)(T) * 64;                 \
    DST[0] = ((const float4*)p_)[0];                           \
    DST[1] = ((const float4*)p_)[1];                           \
    DST[2] = ((const float4*)(p_ + 32))[0];                    \
    DST[3] = ((const float4*)(p_ + 32))[1];                    \
  } while (0)

#define LOAD_W(DST, TILE) do {                                 \
    const uint16_t* q_ = wbase + (size_t)(TILE) * 8192;        \
    DST[0] = *(const short8*)(q_);                             \
    DST[1] = *(const short8*)(q_ + 512);                       \
    DST[2] = *(const short8*)(q_ + 1024);                      \
    DST[3] = *(const short8*)(q_ + 1536);                      \
  } while (0)

#define CVT_WRITE(SRC, BUF) do {                               \
    abuf[BUF][slot0] = pack_bf16x8(SRC[0], SRC[1]);            \
    abuf[BUF][slot1] = pack_bf16x8(SRC[2], SRC[3]);            \
  } while (0)

  // ---- prologue ----
  LOAD_A(aA, 0);
  LOAD_A(aB, 1);
  LOAD_W(wX, 0);            // W(iter 0, half 0)
  CVT_WRITE(aA, 0);
  __syncthreads();

  // Steady state: entering iter T, wX = W(T, half0); A_T in abuf[T&1];
  // A_{T+1} f32 in AVC regs; loads issue >= half-iter before use.
#define STEP(T, AVI, AVC) do {                                                  \
    const int buf_ = (T) & 1;                                                   \
    if ((T) + 2 < NITER) LOAD_A(AVI, (T) + 2);                                  \
    short8 af_[4];                                                              \
    _Pragma("unroll") for (int mi = 0; mi < 4; ++mi)                            \
      af_[mi] = abuf[buf_][mi * 64 + lane];                                     \
    LOAD_W(wY, 2 * (T) + 1);                                                    \
    _Pragma("unroll") for (int mi = 0; mi < 4; ++mi)                            \
      _Pragma("unroll") for (int nj = 0; nj < 4; ++nj)                          \
        acc[mi][nj] = __builtin_amdgcn_mfma_f32_16x16x32_bf16(af_[mi], wX[nj],  \
                                                              acc[mi][nj], 0, 0, 0); \
    _Pragma("unroll") for (int mi = 0; mi < 4; ++mi)                            \
      af_[mi] = abuf[buf_][256 + mi * 64 + lane];                               \
    if ((T) + 1 < NITER) LOAD_W(wX, 2 * (T) + 2);                               \
    _Pragma("unroll") for (int mi = 0; mi < 4; ++mi)                            \
      _Pragma("unroll") for (int nj = 0; nj < 4; ++nj)                          \
        acc[mi][nj] = __builtin_amdgcn_mfma_f32_16x16x32_bf16(af_[mi], wY[nj],  \
                                                              acc[mi][nj], 0, 0, 0); \
    if ((T) + 1 < NITER) CVT_WRITE(AVC, buf_ ^ 1);                              \
    __syncthreads();                                                            \
  } while (0)

#pragma unroll 1
  for (int t = 0; t < NITER; t += 2) {
    STEP(t,     aA, aB);   // loads A_{t+2}->aA, cvt+writes A_{t+1} (aB)
    STEP(t + 1, aB, aA);
  }
#undef STEP
#undef LOAD_A
#undef LOAD_W
#undef CVT_WRITE

  // ---- store partials: C/D layout col=lane&15, row=(lane>>4)*4+reg ----
  float* P = wsP + ((size_t)ks * 4096 + (size_t)mb * 64) * 256;
#pragma unroll
  for (int mi = 0; mi < 4; ++mi)
#pragma unroll
    for (int nj = 0; nj < 4; ++nj)
#pragma unroll
      for (int j = 0; j < 4; ++j) {
        const int rr = mi * 16 + lg * 4 + j;
        const int cc = wave * 64 + nj * 16 + lrow;
        P[(size_t)rr * 256 + cc] = acc[mi][nj][j];
      }
}

// ---------------------------------------------------------------------------
// Kernel 3: reduce KSPLIT partials, add bias, perspective mix, clamp.
// ---------------------------------------------------------------------------
template<int KSPLIT>
__global__ __launch_bounds__(256) void k_reduce(const float* __restrict__ wsP,
                                                const float* __restrict__ us,
                                                const float* __restrict__ them,
                                                const float* __restrict__ bias,
                                                float* __restrict__ out) {
  const int r = blockIdx.x;    // 0..2047
  const int c = threadIdx.x;   // 0..255
  float wd = 0.f, bd = 0.f;
#pragma unroll
  for (int s = 0; s < KSPLIT; ++s) {
    wd += wsP[((size_t)s * 4096 + r) * 256 + c];
    bd += wsP[((size_t)s * 4096 + 2048 + r) * 256 + c];
  }
  const float bi = bias[c];
  const float w = wd + bi;
  const float b = bd + bi;
  const float u = us[r];
  const float t = them[r];
  float o1 = u * w + t * b;
  float o2 = u * b + t * w;
  o1 = fminf(fmaxf(o1, 0.f), 1.f);
  o2 = fminf(fmaxf(o2, 0.f), 1.f);
  out[(size_t)r * 512 + c]       = o1;
  out[(size_t)r * 512 + 256 + c] = o2;
}

extern "C" void kernel_launch(void* const* d_in, const int* in_sizes, int n_in,
                              void* d_out, int out_size, void* d_ws, size_t ws_size,
                              hipStream_t stream) {
  const float* us   = (const float*)d_in[0];
  const float* them = (const float*)d_in[1];
  const float* w_in = (const float*)d_in[2];
  const float* b_in = (const float*)d_in[3];
  const float* W    = (const float*)d_in[4];
  const float* bias = (const float*)d_in[5];
  float* out = (float*)d_out;

  uint16_t* wsW = (uint16_t*)d_ws;
  float*    wsP = (float*)((char*)d_ws + WS_W_BYTES);

  k_convert_w<<<C_NT32, 256, 0, stream>>>(W, wsW);

  const size_t need16 = WS_W_BYTES + (size_t)16 * 4096 * 256 * 4;  // 88.1 MB
  if (ws_size >= need16) {
    k_gemm<16><<<64 * 16, 256, 0, stream>>>(w_in, b_in, wsW, wsP);
    k_reduce<16><<<2048, 256, 0, stream>>>(wsP, us, them, bias, out);
  } else {
    k_gemm<8><<<64 * 8, 256, 0, stream>>>(w_in, b_in, wsW, wsP);
    k_reduce<8><<<2048, 256, 0, stream>>>(wsP, us, them, bias, out);
  }
}